// Round 1
// baseline (158.328 us; speedup 1.0000x reference)
//
#include <hip/hip_runtime.h>

typedef _Float16 f16;
typedef __attribute__((ext_vector_type(8))) _Float16 f16x8;
typedef __attribute__((ext_vector_type(4))) float f32x4;
typedef unsigned int u32;

#define S_      4
#define NPER    12500
#define NF      1024
#define HID     256
#define NSTRUCT 500
#define TM      64

#define GLB __attribute__((address_space(1)))
#define AS3 __attribute__((address_space(3)))

#define WAIT_VM(N)  asm volatile("s_waitcnt vmcnt(" #N ")" ::: "memory")
#define WAIT_LGKM() asm volatile("s_waitcnt lgkmcnt(0)" ::: "memory")
#define SCHED0()    __builtin_amdgcn_sched_barrier(0)
#define BARRIER()   do { __builtin_amdgcn_s_barrier(); SCHED0(); } while (0)

// ---------------------------------------------------------------------------
// Fused weight transpose + fp32->fp16 (all 3 layers, 1 launch) -- unchanged.
// ---------------------------------------------------------------------------
__global__ __launch_bounds__(256) void transpose_all_kernel(
    const float* __restrict__ W1, const float* __restrict__ W2,
    const float* __restrict__ W3,
    f16* __restrict__ w1t, f16* __restrict__ w2t, f16* __restrict__ w3t)
{
  const int z = blockIdx.z;            // layer*4 + species
  const int layer = z >> 2, sp = z & 3;
  const float* in; f16* out; int K;
  if (layer == 0)      { in = W1; out = w1t; K = NF;  }
  else if (layer == 1) { in = W2; out = w2t; K = HID; }
  else                 { in = W3; out = w3t; K = HID; }
  if (blockIdx.x * 64 >= K) return;

  __shared__ float tile[64][65];
  const float* inp = in + (size_t)sp * K * HID;
  f16* outp = out + (size_t)sp * K * HID;
  const int k0 = blockIdx.x * 64;
  const int n0 = blockIdx.y * 64;
  const int t = threadIdx.x;
  {
    const int lk = t >> 2;
    const int nq = (t & 3) * 16;
    const float* src = inp + (size_t)(k0 + lk) * HID + n0 + nq;
    #pragma unroll
    for (int i = 0; i < 4; ++i) {
      float4 v = *(const float4*)(src + i * 4);
      tile[lk][nq + i * 4 + 0] = v.x;
      tile[lk][nq + i * 4 + 1] = v.y;
      tile[lk][nq + i * 4 + 2] = v.z;
      tile[lk][nq + i * 4 + 3] = v.w;
    }
  }
  __syncthreads();
  {
    const int ln = t >> 2;
    const int kq = (t & 3) * 16;
    f16* dst = outp + (size_t)(n0 + ln) * K + k0 + kq;
    f16x8 a, b;
    #pragma unroll
    for (int j = 0; j < 8; ++j) a[j] = (f16)tile[kq + j][ln];
    #pragma unroll
    for (int j = 0; j < 8; ++j) b[j] = (f16)tile[kq + 8 + j][ln];
    *(f16x8*)dst = a;
    *(f16x8*)(dst + 8) = b;
  }
}

// ---------------------------------------------------------------------------
// Fused MLP, occupancy-first restructure (R8):
//  - LDS 48 KB (3x16KB fp32 A tri-buffer; hL 32KB overlays) -> 3 blocks/CU.
//  - B weights: L2 -> registers directly (self-staged LDS B gave no reuse).
//  - L1: gll fp32 A, swizzled source / linear dest; one VM(12) + one barrier
//    per phase (A shared). vmcnt invariant: 12 newest ops = this phase's
//    4 gll(A c+2) + 8 B(c+1) loads, so VM(12) readies B(c) AND drains A(c+1).
//  - Hidden layers: zero interior barriers, zero manual waits (hL read-only,
//    B regs dbuf, compiler inserts counted waits).
// ---------------------------------------------------------------------------

__device__ __forceinline__ void zero_acc(f32x4 (&acc)[4][4]) {
  #pragma unroll
  for (int a = 0; a < 4; ++a)
    #pragma unroll
    for (int b = 0; b < 4; ++b)
      #pragma unroll
      for (int j = 0; j < 4; ++j) acc[a][b][j] = 0.f;
}

// L1 A chunk [64 r][64 k] fp32 staged via gll. Row = 256B = 16 slots of 16B;
// phys slot p holds logical slot p^(row&15). Linear gll dest, swizzled src.
__device__ __forceinline__ void stage_a64(char* aS, const float* fbase, int c,
                                          int row0, int w, int lane)
{
  #pragma unroll
  for (int i = 0; i < 4; ++i) {
    const int row  = i * 16 + w * 4 + (lane >> 4);   // 0..63, distinct
    const int p    = lane & 15;
    const int slog = p ^ (row & 15);
    int rg = row0 + row; if (rg > NPER - 1) rg = NPER - 1;
    const float* gp = fbase + (size_t)rg * NF + c * 64 + slog * 4;
    char* lp = aS + ((i * 16 + w * 4) << 8);         // wave-uniform; HW +lane*16
    __builtin_amdgcn_global_load_lds((const GLB u32*)gp, (AS3 u32*)lp, 16, 0, 0);
  }
}

// B fragments L2 -> regs: 8 x 16B per lane per KC=64 chunk.
// frag(ks,bt): col nn = w*64+bt*16+l15, halves k = c*64 + (ks*4+g)*8.
__device__ __forceinline__ void load_b64(f16x8 (&bf)[8], const f16* wsrc, int c,
                                         int K, int w, int g, int l15)
{
  #pragma unroll
  for (int ks = 0; ks < 2; ++ks)
    #pragma unroll
    for (int bt = 0; bt < 4; ++bt) {
      const int nn = w * 64 + bt * 16 + l15;
      bf[ks * 4 + bt] = *(const f16x8*)(wsrc + (size_t)nn * K + c * 64 + (ks * 4 + g) * 8);
    }
}

// L1 compute: KC=64 chunk, fp32 A from LDS (convert on read), B regs. 32 MFMA.
__device__ __forceinline__ void mfma64_f32a(f32x4 (&acc)[4][4], const char* aS,
                                            const f16x8 (&bf)[8], int g, int l15)
{
  #pragma unroll
  for (int ks = 0; ks < 2; ++ks) {
    f16x8 af[4];
    #pragma unroll
    for (int at = 0; at < 4; ++at) {
      const int rr = at * 16 + l15;
      const int sw = rr & 15;
      const int s0 = ks * 8 + g * 2;
      const f32x4 lo = *(const f32x4*)(aS + rr * 256 + ((s0    ) ^ sw) * 16);
      const f32x4 hi = *(const f32x4*)(aS + rr * 256 + ((s0 + 1) ^ sw) * 16);
      f16x8 a;
      a[0]=(f16)lo[0]; a[1]=(f16)lo[1]; a[2]=(f16)lo[2]; a[3]=(f16)lo[3];
      a[4]=(f16)hi[0]; a[5]=(f16)hi[1]; a[6]=(f16)hi[2]; a[7]=(f16)hi[3];
      af[at] = a;
    }
    #pragma unroll
    for (int at = 0; at < 4; ++at)
      #pragma unroll
      for (int bt = 0; bt < 4; ++bt)
        acc[at][bt] = __builtin_amdgcn_mfma_f32_16x16x32_f16(af[at], bf[ks*4+bt], acc[at][bt], 0, 0, 0);
  }
}

// Hidden compute: KC=64 chunk, A = hL fp16 (xor (row&7)<<4, proven layout),
// B regs. 32 MFMA, no LDS writes -> no barriers needed inside a layer.
__device__ __forceinline__ void mfma64_h(f32x4 (&acc)[4][4], const char* hL, int cH,
                                         const f16x8 (&bf)[8], int g, int l15)
{
  #pragma unroll
  for (int ks = 0; ks < 2; ++ks) {
    f16x8 af[4];
    #pragma unroll
    for (int at = 0; at < 4; ++at) {
      const int rr = at * 16 + l15;
      af[at] = *(const f16x8*)(hL + ((rr * 512 + cH * 128 + ks * 64 + g * 16) ^ ((rr & 7) << 4)));
    }
    #pragma unroll
    for (int at = 0; at < 4; ++at)
      #pragma unroll
      for (int bt = 0; bt < 4; ++bt)
        acc[at][bt] = __builtin_amdgcn_mfma_f32_16x16x32_f16(af[at], bf[ks*4+bt], acc[at][bt], 0, 0, 0);
  }
}

__device__ __forceinline__ void silu_store(f32x4 (&acc)[4][4],
                                           const float* __restrict__ bias,
                                           char* hL, int w, int lane)
{
  const int g = lane >> 4, l15 = lane & 15;
  #pragma unroll
  for (int bt = 0; bt < 4; ++bt) {
    const int col = w * 64 + bt * 16 + l15;
    const float b = bias[col];
    #pragma unroll
    for (int at = 0; at < 4; ++at) {
      #pragma unroll
      for (int j = 0; j < 4; ++j) {
        const int row = at * 16 + g * 4 + j;   // m89-verified C/D mapping
        float x = acc[at][bt][j] + b;
        x = x * __builtin_amdgcn_rcpf(1.f + __expf(-x));
        *(f16*)(hL + (((row * HID + col) * 2) ^ ((row & 7) << 4))) = (f16)x;
      }
    }
  }
}

// Steady L1 phase: stage A(c+2) gll, load B(c+1) regs, VM(12) [readies B(c),
// drains A(c+1)], compute chunk c, lgkm-drain own aS reads, barrier.
#define L1_PH(c, AScur, ASstg, BFcur, BFnxt, DOA, DOB, VMN)   \
  do {                                                         \
    if (DOA) stage_a64(ASstg, fbase, (c) + 2, row0, w, lane);  \
    if (DOB) load_b64(BFnxt, w1s, (c) + 1, NF, w, g, l15);     \
    WAIT_VM(VMN); SCHED0();                                    \
    mfma64_f32a(acc, AScur, BFcur, g, l15);                    \
    WAIT_LGKM(); BARRIER();                                    \
  } while (0)

__global__ __launch_bounds__(256, 3) void mlp_fused_kernel(
    const float* __restrict__ feats,
    const float* __restrict__ b1g,
    const float* __restrict__ b2g,
    const float* __restrict__ b3g,
    const float* __restrict__ w4g,
    const float* __restrict__ b4g,
    const int*   __restrict__ sidxg,
    const f16*   __restrict__ w1t,
    const f16*   __restrict__ w2t,
    const f16*   __restrict__ w3t,
    float*       __restrict__ outg)
{
  __shared__ char arena[48 * 1024];
  char* aS0 = arena;                 // L1 A tri-buffer: 3 x 16 KB fp32
  char* aS1 = arena + 16 * 1024;
  char* aS2 = arena + 32 * 1024;
  char* hL  = arena;                 // hidden: h [64][256] fp16, 32 KB (overlay)

  const int s    = blockIdx.y;
  const int row0 = blockIdx.x * TM;
  const int t    = threadIdx.x;
  const int lane = t & 63;
  const int w    = t >> 6;           // 0..3; wave w owns output cols w*64..+63
  const int g    = lane >> 4;
  const int l15  = lane & 15;

  const int gr   = row0 + (t >> 2);
  const bool valid = gr < NPER;
  const int grc  = valid ? gr : (NPER - 1);
  const float* fbase = feats + (size_t)s * NPER * NF;
  const f16*   w1s   = w1t + (size_t)s * HID * NF;
  const f16*   w2s   = w2t + (size_t)s * HID * HID;
  const f16*   w3s   = w3t + (size_t)s * HID * HID;

  f32x4 acc[4][4];
  f16x8 bfA[8], bfB[8];
  zero_acc(acc);

  // ===== L1 prologue: A0, A1 staged; B0 in flight =====
  stage_a64(aS0, fbase, 0, row0, w, lane);     // 4 gll
  stage_a64(aS1, fbase, 1, row0, w, lane);     // 4 gll
  load_b64(bfA, w1s, 0, NF, w, g, l15);        // 8 loads
  WAIT_VM(12); SCHED0();                       // drain A0 (leaves A1+B0)
  BARRIER();

  // ===== L1: 16 phases, KC=64, tri-buffered A, reg-dbuf B =====
  L1_PH(0,  aS0, aS2, bfA, bfB, 1, 1, 12);
  L1_PH(1,  aS1, aS0, bfB, bfA, 1, 1, 12);
  L1_PH(2,  aS2, aS1, bfA, bfB, 1, 1, 12);
  L1_PH(3,  aS0, aS2, bfB, bfA, 1, 1, 12);
  L1_PH(4,  aS1, aS0, bfA, bfB, 1, 1, 12);
  L1_PH(5,  aS2, aS1, bfB, bfA, 1, 1, 12);
  L1_PH(6,  aS0, aS2, bfA, bfB, 1, 1, 12);
  L1_PH(7,  aS1, aS0, bfB, bfA, 1, 1, 12);
  L1_PH(8,  aS2, aS1, bfA, bfB, 1, 1, 12);
  L1_PH(9,  aS0, aS2, bfB, bfA, 1, 1, 12);
  L1_PH(10, aS1, aS0, bfA, bfB, 1, 1, 12);
  L1_PH(11, aS2, aS1, bfB, bfA, 1, 1, 12);
  L1_PH(12, aS0, aS2, bfA, bfB, 1, 1, 12);
  L1_PH(13, aS1, aS0, bfB, bfA, 1, 1, 12);
  L1_PH(14, aS2, aS0, bfA, bfB, 0, 1, 8);      // no A stage; B15 -> bfB
  { // phase 15: compute aS0/bfB; early-issue W2 chunk 0 into bfA
    WAIT_VM(0); SCHED0();
    mfma64_f32a(acc, aS0, bfB, g, l15);
    load_b64(bfA, w2s, 0, HID, w, g, l15);
    WAIT_LGKM(); BARRIER();
  }

  // ===== L1 -> L2: write h over dead aS0/aS1 =====
  silu_store(acc, b1g + s * HID, hL, w, lane);
  zero_acc(acc);
  WAIT_LGKM(); BARRIER();

  // ===== Layer 2: 4 chunks KC=64, barrier-free, reg-dbuf B =====
  load_b64(bfB, w2s, 1, HID, w, g, l15);
  mfma64_h(acc, hL, 0, bfA, g, l15);
  load_b64(bfA, w2s, 2, HID, w, g, l15);
  mfma64_h(acc, hL, 1, bfB, g, l15);
  load_b64(bfB, w2s, 3, HID, w, g, l15);
  mfma64_h(acc, hL, 2, bfA, g, l15);
  load_b64(bfA, w3s, 0, HID, w, g, l15);       // prefetch L3 chunk 0
  mfma64_h(acc, hL, 3, bfB, g, l15);
  BARRIER();                                   // all waves done reading hL
  silu_store(acc, b2g + s * HID, hL, w, lane);
  zero_acc(acc);
  WAIT_LGKM(); BARRIER();                      // hL published

  // ===== Layer 3: 4 chunks, barrier-free =====
  load_b64(bfB, w3s, 1, HID, w, g, l15);
  mfma64_h(acc, hL, 0, bfA, g, l15);
  load_b64(bfA, w3s, 2, HID, w, g, l15);
  mfma64_h(acc, hL, 1, bfB, g, l15);
  load_b64(bfB, w3s, 3, HID, w, g, l15);
  mfma64_h(acc, hL, 2, bfA, g, l15);
  mfma64_h(acc, hL, 3, bfB, g, l15);
  BARRIER();
  silu_store(acc, b3g + s * HID, hL, w, lane);
  WAIT_LGKM(); BARRIER();

  // ===== Layer 4: e = h @ W4 + b4; segment-sum via atomicAdd =====
  {
    const int row = t >> 2;
    const int q   = t & 3;
    const float* w4 = w4g + s * HID;
    float sum = 0.f;
    #pragma unroll
    for (int j8 = 0; j8 < 64; j8 += 8) {
      const int k = q * 64 + j8;
      f16x8 hv = *(const f16x8*)(hL + (((row * HID + k) * 2) ^ ((row & 7) << 4)));
      float4 wa = *(const float4*)(w4 + k);
      float4 wb = *(const float4*)(w4 + k + 4);
      sum += (float)hv[0] * wa.x + (float)hv[1] * wa.y + (float)hv[2] * wa.z + (float)hv[3] * wa.w
           + (float)hv[4] * wb.x + (float)hv[5] * wb.y + (float)hv[6] * wb.z + (float)hv[7] * wb.w;
    }
    sum += __shfl_xor(sum, 1);
    sum += __shfl_xor(sum, 2);
    if (q == 0 && valid) {
      atomicAdd(&outg[sidxg[s * NPER + gr]], sum + b4g[s]);
    }
  }
}

// ---------------------------------------------------------------------------
extern "C" void kernel_launch(void* const* d_in, const int* in_sizes, int n_in,
                              void* d_out, int out_size, void* d_ws, size_t ws_size,
                              hipStream_t stream)
{
  const float* feats = (const float*)d_in[0];
  const float* W1    = (const float*)d_in[1];
  const float* b1    = (const float*)d_in[2];
  const float* W2    = (const float*)d_in[3];
  const float* b2    = (const float*)d_in[4];
  const float* W3    = (const float*)d_in[5];
  const float* b3    = (const float*)d_in[6];
  const float* W4    = (const float*)d_in[7];
  const float* b4    = (const float*)d_in[8];
  const int*   sidx  = (const int*)d_in[9];
  float* out = (float*)d_out;

  f16* w1t = (f16*)d_ws;                              // [S][256][1024] fp16
  f16* w2t = w1t + (size_t)S_ * HID * NF;             // [S][256][256]  fp16
  f16* w3t = w2t + (size_t)S_ * HID * HID;            // [S][256][256]  fp16

  hipMemsetAsync(d_out, 0, NSTRUCT * sizeof(float), stream);
  transpose_all_kernel<<<dim3(16, 4, 12), 256, 0, stream>>>(W1, W2, W3, w1t, w2t, w3t);
  mlp_fused_kernel<<<dim3((NPER + TM - 1) / TM, S_), 256, 0, stream>>>(
      feats, b1, b2, b3, W4, b4, sidx, w1t, w2t, w3t, out);
}